// Round 5
// baseline (947.994 us; speedup 1.0000x reference)
//
#include <hip/hip_runtime.h>

#define NN 50000
#define EE 1600000
#define MM 2
#define DIN 2000
#define H1 500
#define LAT 128
#define DECF 64
#define KTOT (MM*DIN)        // 4000
#define KSTEPS (KTOT/32)     // 125
#define NTILES (NN/16)       // 3125 exact
#define GEMM_BLKS 782        // 782*4 = 3128 waves >= 3125 tiles, all co-resident
#define ESLICE ((EE + GEMM_BLKS - 1)/GEMM_BLKS)   // 2047 edges per block prologue
#define EPSBN 1e-5f

typedef float f32x4 __attribute__((ext_vector_type(4)));
typedef short short8v __attribute__((ext_vector_type(8)));
typedef unsigned int u32x2 __attribute__((ext_vector_type(2)));

__device__ __forceinline__ unsigned int pkbf(float a, float b){
  unsigned int ua = __float_as_uint(a), ub = __float_as_uint(b);
  ua = (ua + 0x7FFFu + ((ua>>16)&1u)) >> 16;
  ub = (ub + 0x7FFFu + ((ub>>16)&1u)) & 0xFFFF0000u;
  return ua | ub;
}
__device__ __forceinline__ unsigned short pk1(float a){
  unsigned int u = __float_as_uint(a);
  return (unsigned short)((u + 0x7FFFu + ((u>>16)&1u)) >> 16);
}
__device__ __forceinline__ float bfe0(unsigned int w){ return __uint_as_float(w<<16); }
__device__ __forceinline__ float bfe1(unsigned int w){ return __uint_as_float(w & 0xFFFF0000u); }

// ---- prepA: T[m][k][d] = sum_l W2[m][k][l]*a2[m][l]*Wd[m][l][d], a2 inline ----
__global__ __launch_bounds__(256) void prepA(const float* __restrict__ W2,const float* __restrict__ Wd,
                      const float* __restrict__ g2,const float* __restrict__ v2,
                      float* __restrict__ T){
  __shared__ float a2[LAT];
  int m = (blockIdx.x*4) / H1;
  if (threadIdx.x < LAT)
    a2[threadIdx.x] = g2[m*LAT+threadIdx.x]*rsqrtf(v2[m*LAT+threadIdx.x]+EPSBN);
  __syncthreads();
  int g = blockIdx.x*256 + threadIdx.x;     // grid exact: 64000/256 = 250
  int d = g & 63; int mk = g >> 6; int k = mk % H1;
  const float* w2 = W2 + (size_t)(m*H1 + k)*LAT;
  const float* wd = Wd + (size_t)m*LAT*DECF + d;
  float acc = 0.f;
  for (int l = 0; l < LAT; ++l) acc += w2[l]*a2[l]*wd[(size_t)l*DECF];
  T[g] = acc;
}

// ---- prepB: Weff (bf16, B-fragment order), a1 inline ----
__global__ __launch_bounds__(256) void prepB(const float* __restrict__ W1,const float* __restrict__ g1,
                      const float* __restrict__ v1,const float* __restrict__ T,
                      unsigned short* __restrict__ WB){
  __shared__ float a1[H1];
  int m = (blockIdx.x*4) / DIN;
  for (int k = threadIdx.x; k < H1; k += 256)
    a1[k] = g1[m*H1+k]*rsqrtf(v1[m*H1+k]+EPSBN);
  __syncthreads();
  int g = blockIdx.x*256 + threadIdx.x;     // grid exact: 256000/256 = 1000
  int d = g & 63; int mi = g >> 6; int i = mi % DIN;
  const float* w1 = W1 + (size_t)(m*DIN + i)*H1;
  const float* t  = T + (size_t)m*H1*DECF + d;
  float acc = 0.f;
  for (int k = 0; k < H1; ++k) acc += w1[k]*a1[k]*t[(size_t)k*DECF];
  acc *= 0.5f;
  unsigned int u = __float_as_uint(acc);
  unsigned short bf = (unsigned short)((u + 0x7FFFu + ((u>>16)&1u)) >> 16);
  int kc = m*DIN + i;
  int s = kc >> 5, kl = kc & 31;
  int laneB = ((kl>>3)<<4) | (d & 15);
  int t4 = d >> 4;
  WB[((size_t)((s*4 + t4)*64 + laneB))*8 + (kl & 7)] = bf;
}

// ---- prepC: cbar[d] = 0.5 * sum_m ( c1@T + c2@Wd + bd ) ----
__global__ void prepC(const float* __restrict__ b1,const float* __restrict__ g1,const float* __restrict__ be1,
                      const float* __restrict__ m1,const float* __restrict__ v1,
                      const float* __restrict__ b2,const float* __restrict__ g2,const float* __restrict__ be2,
                      const float* __restrict__ m2,const float* __restrict__ v2,
                      const float* __restrict__ T,const float* __restrict__ Wd,
                      const float* __restrict__ bd, float* __restrict__ cbar){
  __shared__ float part[128];
  int d = threadIdx.x & 63, h = threadIdx.x >> 6;
  float s = 0.f;
  for (int m = 0; m < MM; ++m){
    if (h == 0) s += bd[m*DECF + d];
    const float* t = T + (size_t)m*H1*DECF + d;
    for (int k = h*(H1/2); k < (h+1)*(H1/2); ++k){
      float a = g1[m*H1+k]*rsqrtf(v1[m*H1+k]+EPSBN);
      float c = (b1[m*H1+k]-m1[m*H1+k])*a + be1[m*H1+k];
      s += c*t[(size_t)k*DECF];
    }
    const float* wd = Wd + (size_t)m*LAT*DECF + d;
    for (int l = h*(LAT/2); l < (h+1)*(LAT/2); ++l){
      float a = g2[m*LAT+l]*rsqrtf(v2[m*LAT+l]+EPSBN);
      float c = (b2[m*LAT+l]-m2[m*LAT+l])*a + be2[m*LAT+l];
      s += c*wd[(size_t)l*DECF];
    }
  }
  part[threadIdx.x] = s;
  __syncthreads();
  if (h == 0) cbar[d] = 0.5f*(part[d] + part[64+d]);
}

__global__ __launch_bounds__(1024) void scan1(const int* __restrict__ deg, int* __restrict__ rp,
                      int* __restrict__ bsum, int n){
  __shared__ int sm[1024];
  int i = blockIdx.x*1024 + threadIdx.x;
  int v = (i < n) ? deg[i] : 0;
  sm[threadIdx.x] = v; __syncthreads();
  for (int off=1; off<1024; off<<=1){
    int t = (threadIdx.x >= off) ? sm[threadIdx.x-off] : 0;
    __syncthreads();
    sm[threadIdx.x] += t;
    __syncthreads();
  }
  if (i < n) rp[i] = sm[threadIdx.x] - v;
  if (threadIdx.x == 1023) bsum[blockIdx.x] = sm[1023];
}

__global__ void scan3n(int* __restrict__ rp, const int* __restrict__ bsum,
                       const int* __restrict__ dout, const int* __restrict__ din,
                       float* __restrict__ csrc, float* __restrict__ cdst){
  int i = blockIdx.x*blockDim.x + threadIdx.x;
  if (i >= NN) return;
  int b = i >> 10;
  int base = 0;
  for (int j = 0; j < b; ++j) base += bsum[j];
  rp[i] += base;
  if (i == NN-1) rp[NN] = EE;
  int a = dout[i]; if (a < 1) a = 1;
  int dd = din[i]; if (dd < 1) dd = 1;
  csrc[i] = rsqrtf((float)a);
  cdst[i] = rsqrtf((float)dd);
}

__global__ void scatk(const int* __restrict__ src,const int* __restrict__ dst,
                      const int* __restrict__ rp,int* __restrict__ cur,int* __restrict__ ss){
  int e = blockIdx.x*blockDim.x + threadIdx.x;
  if (e >= EE) return;
  int d = dst[e];
  int p = rp[d] + atomicAdd(&cur[d], 1);
  ss[p] = src[e];
}

// ---- static GEMM (782 blocks, 1 wave = 1 tile, all co-resident) + deg prologue ----
// nf_raw[n][d] = bf16( 0.5*sum_m x_m[n,:]@Weff_m[:,d] + cbar[d] )   (csrc applied in fgd1)
__global__ __launch_bounds__(256,4) void gemm_deg(
    const float* __restrict__ x, const short8v* __restrict__ WB,
    const float* __restrict__ cbar,
    unsigned short* __restrict__ nfb,
    const int* __restrict__ src, const int* __restrict__ dst,
    int* __restrict__ dout, int* __restrict__ din)
{
  // degree histogram slice, overlapped with gemm execution of other waves
  {
    int eBeg = blockIdx.x*ESLICE;
    int eEnd = eBeg + ESLICE; if (eEnd > EE) eEnd = EE;
    for (int e = eBeg + threadIdx.x; e < eEnd; e += 256){
      atomicAdd(&dout[src[e]], 1);
      atomicAdd(&din[dst[e]], 1);
    }
  }
  const int t = blockIdx.x*4 + (threadIdx.x >> 6);
  if (t >= NTILES) return;
  const int lane = threadIdx.x & 63;
  const int r = lane & 15;
  const int kg = (lane >> 4) << 3;             // k-slot base: 0,8,16,24
  const int rg = (lane >> 4) << 2;             // D row group: 0,4,8,12
  const float cb0 = cbar[r], cb1 = cbar[16+r], cb2 = cbar[32+r], cb3 = cbar[48+r];
  const int n0 = t*16;
  const float* xrow = x + (size_t)(n0 + r) * DIN;

  f32x4 acc0 = {0.f,0.f,0.f,0.f}, acc1 = acc0, acc2 = acc0, acc3 = acc0;
  f32x4 A0c, A1c; short8v B0c, B1c, B2c, B3c;
  {
    const float* p = xrow + kg;                // s=0 always in modality 0
    A0c = *(const f32x4*)p; A1c = *(const f32x4*)(p+4);
    const short8v* bp = WB + lane;
    B0c = bp[0]; B1c = bp[64]; B2c = bp[128]; B3c = bp[192];
  }
  for (int s = 0; s < KSTEPS-1; ++s){
    f32x4 A0n, A1n; short8v B0n, B1n, B2n, B3n;
    {
      int kr = (s+1)*32 + kg;
      const float* p = (kr < DIN) ? (xrow + kr)
                                  : (xrow + (size_t)(NN-1)*DIN + kr); // modality 1
      A0n = *(const f32x4*)p; A1n = *(const f32x4*)(p+4);
      const short8v* bp = WB + (size_t)(s+1)*256 + lane;
      B0n = bp[0]; B1n = bp[64]; B2n = bp[128]; B3n = bp[192];
    }
    union { short8v v; unsigned int u[4]; } AF;
    AF.u[0]=pkbf(A0c[0],A0c[1]); AF.u[1]=pkbf(A0c[2],A0c[3]);
    AF.u[2]=pkbf(A1c[0],A1c[1]); AF.u[3]=pkbf(A1c[2],A1c[3]);
    acc0 = __builtin_amdgcn_mfma_f32_16x16x32_bf16(AF.v, B0c, acc0, 0,0,0);
    acc1 = __builtin_amdgcn_mfma_f32_16x16x32_bf16(AF.v, B1c, acc1, 0,0,0);
    acc2 = __builtin_amdgcn_mfma_f32_16x16x32_bf16(AF.v, B2c, acc2, 0,0,0);
    acc3 = __builtin_amdgcn_mfma_f32_16x16x32_bf16(AF.v, B3c, acc3, 0,0,0);
    A0c=A0n; A1c=A1n; B0c=B0n; B1c=B1n; B2c=B2n; B3c=B3n;
  }
  {
    union { short8v v; unsigned int u[4]; } AF;
    AF.u[0]=pkbf(A0c[0],A0c[1]); AF.u[1]=pkbf(A0c[2],A0c[3]);
    AF.u[2]=pkbf(A1c[0],A1c[1]); AF.u[3]=pkbf(A1c[2],A1c[3]);
    acc0 = __builtin_amdgcn_mfma_f32_16x16x32_bf16(AF.v, B0c, acc0, 0,0,0);
    acc1 = __builtin_amdgcn_mfma_f32_16x16x32_bf16(AF.v, B1c, acc1, 0,0,0);
    acc2 = __builtin_amdgcn_mfma_f32_16x16x32_bf16(AF.v, B2c, acc2, 0,0,0);
    acc3 = __builtin_amdgcn_mfma_f32_16x16x32_bf16(AF.v, B3c, acc3, 0,0,0);
  }
  #pragma unroll
  for (int rr = 0; rr < 4; ++rr){
    int rowD = n0 + rg + rr;
    unsigned short* o = nfb + (size_t)rowD*64 + r;
    o[0]  = pk1(acc0[rr] + cb0);
    o[16] = pk1(acc1[rr] + cb1);
    o[32] = pk1(acc2[rr] + cb2);
    o[48] = pk1(acc3[rr] + cb3);
  }
}

#define ACC_CS(sv, idx) { float c_ = csrc[idx]; \
  u32x2 w_ = *(const u32x2*)(nfb + (size_t)(idx)*64 + cc); \
  sv.x += c_*bfe0(w_.x); sv.y += c_*bfe1(w_.x); \
  sv.z += c_*bfe0(w_.y); sv.w += c_*bfe1(w_.y); }

#define ACC_NC(sv, idx) { \
  u32x2 w_ = *(const u32x2*)(hpb + (size_t)(idx)*64 + cc); \
  sv.x += bfe0(w_.x); sv.y += bfe1(w_.x); \
  sv.z += bfe0(w_.y); sv.w += bfe1(w_.y); }

#define RED16(sv) \
  sv.x += __shfl_xor(sv.x,16); sv.y += __shfl_xor(sv.y,16); \
  sv.z += __shfl_xor(sv.z,16); sv.w += __shfl_xor(sv.w,16); \
  sv.x += __shfl_xor(sv.x,32); sv.y += __shfl_xor(sv.y,32); \
  sv.z += __shfl_xor(sv.z,32); sv.w += __shfl_xor(sv.w,32);

// ---- fused gather(csrc-scaled, bf16) + dense1 -> hp (bf16), dual node streams ----
__global__ __launch_bounds__(512,4) void fgd1(const unsigned short* __restrict__ nfb,
                      const int* __restrict__ rp,const int* __restrict__ ss,
                      const float* __restrict__ Wg1,const float* __restrict__ bg1,
                      const float* __restrict__ csrc,const float* __restrict__ cdst,
                      unsigned short* __restrict__ hpb){
  __shared__ float W[64*64];
  for (int i = threadIdx.x; i < 64*64; i += 512) W[i] = Wg1[i];
  __syncthreads();
  int wave = threadIdx.x >> 6, lane = threadIdx.x & 63;
  int q = lane >> 4, cc = (lane & 15)*4;       // 4 ushorts (8B) per lane
  const int WVS = 512*8;                       // 4096 waves
  int wid = blockIdx.x*8 + wave;
  for (int n = wid; n < NN; n += 2*WVS){
    int n2 = n + WVS;
    bool has2 = (n2 < NN);
    f32x4 sA = {0.f,0.f,0.f,0.f}, sB = sA;
    int eA = rp[n] + q, endA = rp[n+1];
    int eB = 0, endB = 0;
    if (has2){ eB = rp[n2] + q; endB = rp[n2+1]; }
    // interleaved 4-deep on both streams: 8 independent rows in flight
    while (eA + 12 < endA && eB + 12 < endB){
      int a0=ss[eA],a1=ss[eA+4],a2=ss[eA+8],a3=ss[eA+12];
      int b0=ss[eB],b1=ss[eB+4],b2=ss[eB+8],b3=ss[eB+12];
      ACC_CS(sA,a0); ACC_CS(sA,a1); ACC_CS(sA,a2); ACC_CS(sA,a3);
      ACC_CS(sB,b0); ACC_CS(sB,b1); ACC_CS(sB,b2); ACC_CS(sB,b3);
      eA += 16; eB += 16;
    }
    for (; eA + 12 < endA; eA += 16){
      int a0=ss[eA],a1=ss[eA+4],a2=ss[eA+8],a3=ss[eA+12];
      ACC_CS(sA,a0); ACC_CS(sA,a1); ACC_CS(sA,a2); ACC_CS(sA,a3);
    }
    for (; eB + 12 < endB; eB += 16){
      int b0=ss[eB],b1=ss[eB+4],b2=ss[eB+8],b3=ss[eB+12];
      ACC_CS(sB,b0); ACC_CS(sB,b1); ACC_CS(sB,b2); ACC_CS(sB,b3);
    }
    for (; eA < endA; eA += 4){ int a0 = ss[eA]; ACC_CS(sA,a0); }
    for (; eB < endB; eB += 4){ int b0 = ss[eB]; ACC_CS(sB,b0); }
    RED16(sA); RED16(sB);
    float acc = 0.f, acc2 = 0.f;
    #pragma unroll
    for (int l16 = 0; l16 < 16; ++l16){
      acc += __shfl(sA.x,l16) * W[(4*l16+0)*64 + lane];
      acc += __shfl(sA.y,l16) * W[(4*l16+1)*64 + lane];
      acc += __shfl(sA.z,l16) * W[(4*l16+2)*64 + lane];
      acc += __shfl(sA.w,l16) * W[(4*l16+3)*64 + lane];
      acc2 += __shfl(sB.x,l16) * W[(4*l16+0)*64 + lane];
      acc2 += __shfl(sB.y,l16) * W[(4*l16+1)*64 + lane];
      acc2 += __shfl(sB.z,l16) * W[(4*l16+2)*64 + lane];
      acc2 += __shfl(sB.w,l16) * W[(4*l16+3)*64 + lane];
    }
    float bg = bg1[lane];
    hpb[(size_t)n*64 + lane] = pk1(fmaxf(cdst[n]*acc + bg, 0.f) * csrc[n]);
    if (has2)
      hpb[(size_t)n2*64 + lane] = pk1(fmaxf(cdst[n2]*acc2 + bg, 0.f) * csrc[n2]);
  }
}

// ---- fused gather(bf16, pre-scaled hp) + dense2 -> score (fp32), dual node streams ----
__global__ __launch_bounds__(512,4) void fgd2(const unsigned short* __restrict__ hpb,
                      const int* __restrict__ rp,const int* __restrict__ ss,
                      const float* __restrict__ Wg2,const float* __restrict__ bg2,
                      const float* __restrict__ cdst,float* __restrict__ score){
  __shared__ float W[64*16];
  for (int i = threadIdx.x; i < 64*16; i += 512) W[i] = Wg2[i];
  __syncthreads();
  int wave = threadIdx.x >> 6, lane = threadIdx.x & 63;
  int q = lane >> 4, cc = (lane & 15)*4;
  const int WVS = 512*8;
  int wid = blockIdx.x*8 + wave;
  for (int n = wid; n < NN; n += 2*WVS){
    int n2 = n + WVS;
    bool has2 = (n2 < NN);
    f32x4 sA = {0.f,0.f,0.f,0.f}, sB = sA;
    int eA = rp[n] + q, endA = rp[n+1];
    int eB = 0, endB = 0;
    if (has2){ eB = rp[n2] + q; endB = rp[n2+1]; }
    while (eA + 12 < endA && eB + 12 < endB){
      int a0=ss[eA],a1=ss[eA+4],a2=ss[eA+8],a3=ss[eA+12];
      int b0=ss[eB],b1=ss[eB+4],b2=ss[eB+8],b3=ss[eB+12];
      ACC_NC(sA,a0); ACC_NC(sA,a1); ACC_NC(sA,a2); ACC_NC(sA,a3);
      ACC_NC(sB,b0); ACC_NC(sB,b1); ACC_NC(sB,b2); ACC_NC(sB,b3);
      eA += 16; eB += 16;
    }
    for (; eA + 12 < endA; eA += 16){
      int a0=ss[eA],a1=ss[eA+4],a2=ss[eA+8],a3=ss[eA+12];
      ACC_NC(sA,a0); ACC_NC(sA,a1); ACC_NC(sA,a2); ACC_NC(sA,a3);
    }
    for (; eB + 12 < endB; eB += 16){
      int b0=ss[eB],b1=ss[eB+4],b2=ss[eB+8],b3=ss[eB+12];
      ACC_NC(sB,b0); ACC_NC(sB,b1); ACC_NC(sB,b2); ACC_NC(sB,b3);
    }
    for (; eA < endA; eA += 4){ int a0 = ss[eA]; ACC_NC(sA,a0); }
    for (; eB < endB; eB += 4){ int b0 = ss[eB]; ACC_NC(sB,b0); }
    RED16(sA); RED16(sB);
    int c = lane & 15;
    float acc = 0.f, acc2 = 0.f;
    #pragma unroll
    for (int l16 = 0; l16 < 16; ++l16){
      acc += __shfl(sA.x,l16) * W[(4*l16+0)*16 + c];
      acc += __shfl(sA.y,l16) * W[(4*l16+1)*16 + c];
      acc += __shfl(sA.z,l16) * W[(4*l16+2)*16 + c];
      acc += __shfl(sA.w,l16) * W[(4*l16+3)*16 + c];
      acc2 += __shfl(sB.x,l16) * W[(4*l16+0)*16 + c];
      acc2 += __shfl(sB.y,l16) * W[(4*l16+1)*16 + c];
      acc2 += __shfl(sB.z,l16) * W[(4*l16+2)*16 + c];
      acc2 += __shfl(sB.w,l16) * W[(4*l16+3)*16 + c];
    }
    if (lane < 16){
      score[(size_t)n*16 + lane] = cdst[n]*acc + bg2[lane];
      if (has2) score[(size_t)n2*16 + lane] = cdst[n2]*acc2 + bg2[lane];
    }
  }
}

extern "C" void kernel_launch(void* const* d_in, const int* in_sizes, int n_in,
                              void* d_out, int out_size, void* d_ws, size_t ws_size,
                              hipStream_t stream){
  const float* x   = (const float*)d_in[0];
  const int* src   = (const int*)d_in[1];
  const int* dst   = (const int*)d_in[2];
  const float* W1  = (const float*)d_in[3];
  const float* b1  = (const float*)d_in[4];
  const float* g1  = (const float*)d_in[5];
  const float* be1 = (const float*)d_in[6];
  const float* m1  = (const float*)d_in[7];
  const float* v1  = (const float*)d_in[8];
  const float* W2  = (const float*)d_in[9];
  const float* b2  = (const float*)d_in[10];
  const float* g2  = (const float*)d_in[11];
  const float* be2 = (const float*)d_in[12];
  const float* m2  = (const float*)d_in[13];
  const float* v2  = (const float*)d_in[14];
  const float* Wd  = (const float*)d_in[15];
  const float* bd  = (const float*)d_in[16];
  const float* Wg1 = (const float*)d_in[17];
  const float* bg1 = (const float*)d_in[18];
  const float* Wg2 = (const float*)d_in[19];
  const float* bg2 = (const float*)d_in[20];
  float* score = (float*)d_out;

  char* w = (char*)d_ws;
  size_t off = 0;
  auto alc = [&](size_t b){ size_t c = off; off += (b + 255) & ~(size_t)255; return c; };
  // zero-init region: dout, din, cur (single memset)
  size_t o_dout = alc((size_t)NN*4), o_din = alc((size_t)NN*4), o_cur = alc((size_t)NN*4);
  size_t zspan = off;
  size_t o_rp  = alc((size_t)(NN+1)*4), o_bsum = alc(256*4);
  size_t o_csrc = alc((size_t)NN*4), o_cdst = alc((size_t)NN*4);
  size_t o_T = alc((size_t)MM*H1*DECF*4), o_cbar = alc(DECF*4);
  size_t o_WB = alc((size_t)MM*DIN*DECF*2);
  size_t o_ss = alc((size_t)EE*4);
  size_t o_nf = alc((size_t)NN*64*2);   // bf16
  size_t o_hp = alc((size_t)NN*64*2);   // bf16

  int* dout = (int*)(w+o_dout); int* din = (int*)(w+o_din); int* cur = (int*)(w+o_cur);
  int* rp = (int*)(w+o_rp); int* bsum = (int*)(w+o_bsum);
  float* csrc = (float*)(w+o_csrc); float* cdst = (float*)(w+o_cdst);
  float* T = (float*)(w+o_T); float* cbar = (float*)(w+o_cbar);
  unsigned short* WBu = (unsigned short*)(w+o_WB);
  int* ss = (int*)(w+o_ss);
  unsigned short* nfb = (unsigned short*)(w+o_nf);
  unsigned short* hpb = (unsigned short*)(w+o_hp);
  (void)WBu;

  hipMemsetAsync(w, 0, zspan, stream);

  prepA<<<(MM*H1*DECF)/256,256,0,stream>>>(W2,Wd,g2,v2,T);
  prepB<<<(MM*DIN*DECF)/256,256,0,stream>>>(W1,g1,v1,T,(unsigned short*)(w+o_WB));
  prepC<<<1,128,0,stream>>>(b1,g1,be1,m1,v1,b2,g2,be2,m2,v2,T,Wd,bd,cbar);

  gemm_deg<<<GEMM_BLKS,256,0,stream>>>(x,(const short8v*)(w+o_WB),cbar,
                                       nfb,src,dst,dout,din);

  int nb = (NN+1023)/1024;
  scan1<<<nb,1024,0,stream>>>(din,rp,bsum,NN);
  scan3n<<<(NN+255)/256,256,0,stream>>>(rp,bsum,dout,din,csrc,cdst);
  scatk<<<(EE+255)/256,256,0,stream>>>(src,dst,rp,cur,ss);

  fgd1<<<512,512,0,stream>>>(nfb,rp,ss,Wg1,bg1,csrc,cdst,hpb);
  fgd2<<<512,512,0,stream>>>(hpb,rp,ss,Wg2,bg2,cdst,score);
}

// Round 6
// 714.910 us; speedup vs baseline: 1.3260x; 1.3260x over previous
//
#include <hip/hip_runtime.h>

#define NN 50000
#define EE 1600000
#define MM 2
#define DIN 2000
#define H1 500
#define LAT 128
#define DECF 64
#define KTOT (MM*DIN)        // 4000
#define KSTEPS (KTOT/32)     // 125
#define NTILES (NN/16)       // 3125 exact
#define GEMM_BLKS 768
#define DEG_BLKS 256
#define EPSBN 1e-5f

typedef float f32x4 __attribute__((ext_vector_type(4)));
typedef float f32x8 __attribute__((ext_vector_type(8)));
typedef short short8v __attribute__((ext_vector_type(8)));
typedef unsigned int u32x4 __attribute__((ext_vector_type(4)));

__device__ __forceinline__ unsigned int pkbf(float a, float b){
  unsigned int ua = __float_as_uint(a), ub = __float_as_uint(b);
  ua = (ua + 0x7FFFu + ((ua>>16)&1u)) >> 16;
  ub = (ub + 0x7FFFu + ((ub>>16)&1u)) & 0xFFFF0000u;
  return ua | ub;
}
__device__ __forceinline__ unsigned short pk1(float a){
  unsigned int u = __float_as_uint(a);
  return (unsigned short)((u + 0x7FFFu + ((u>>16)&1u)) >> 16);
}
__device__ __forceinline__ float bfe0(unsigned int w){ return __uint_as_float(w<<16); }
__device__ __forceinline__ float bfe1(unsigned int w){ return __uint_as_float(w & 0xFFFF0000u); }

// ---- prepA: T[m][k][d] = sum_l W2[m][k][l]*a2[m][l]*Wd[m][l][d], a2 inline ----
__global__ __launch_bounds__(256) void prepA(const float* __restrict__ W2,const float* __restrict__ Wd,
                      const float* __restrict__ g2,const float* __restrict__ v2,
                      float* __restrict__ T){
  __shared__ float a2[LAT];
  int m = (blockIdx.x*4) / H1;
  if (threadIdx.x < LAT)
    a2[threadIdx.x] = g2[m*LAT+threadIdx.x]*rsqrtf(v2[m*LAT+threadIdx.x]+EPSBN);
  __syncthreads();
  int g = blockIdx.x*256 + threadIdx.x;     // grid exact: 64000/256 = 250
  int d = g & 63; int mk = g >> 6; int k = mk % H1;
  const float* w2 = W2 + (size_t)(m*H1 + k)*LAT;
  const float* wd = Wd + (size_t)m*LAT*DECF + d;
  float acc = 0.f;
  for (int l = 0; l < LAT; ++l) acc += w2[l]*a2[l]*wd[(size_t)l*DECF];
  T[g] = acc;
}

// ---- prepB: Weff (bf16, B-fragment order), a1 inline ----
__global__ __launch_bounds__(256) void prepB(const float* __restrict__ W1,const float* __restrict__ g1,
                      const float* __restrict__ v1,const float* __restrict__ T,
                      unsigned short* __restrict__ WB){
  __shared__ float a1[H1];
  int m = (blockIdx.x*4) / DIN;
  for (int k = threadIdx.x; k < H1; k += 256)
    a1[k] = g1[m*H1+k]*rsqrtf(v1[m*H1+k]+EPSBN);
  __syncthreads();
  int g = blockIdx.x*256 + threadIdx.x;     // grid exact: 256000/256 = 1000
  int d = g & 63; int mi = g >> 6; int i = mi % DIN;
  const float* w1 = W1 + (size_t)(m*DIN + i)*H1;
  const float* t  = T + (size_t)m*H1*DECF + d;
  float acc = 0.f;
  for (int k = 0; k < H1; ++k) acc += w1[k]*a1[k]*t[(size_t)k*DECF];
  acc *= 0.5f;
  unsigned int u = __float_as_uint(acc);
  unsigned short bf = (unsigned short)((u + 0x7FFFu + ((u>>16)&1u)) >> 16);
  int kc = m*DIN + i;
  int s = kc >> 5, kl = kc & 31;
  int laneB = ((kl>>3)<<4) | (d & 15);
  int t4 = d >> 4;
  WB[((size_t)((s*4 + t4)*64 + laneB))*8 + (kl & 7)] = bf;
}

// ---- prepC: cbar[d] = 0.5 * sum_m ( c1@T + c2@Wd + bd ) ----
__global__ void prepC(const float* __restrict__ b1,const float* __restrict__ g1,const float* __restrict__ be1,
                      const float* __restrict__ m1,const float* __restrict__ v1,
                      const float* __restrict__ b2,const float* __restrict__ g2,const float* __restrict__ be2,
                      const float* __restrict__ m2,const float* __restrict__ v2,
                      const float* __restrict__ T,const float* __restrict__ Wd,
                      const float* __restrict__ bd, float* __restrict__ cbar){
  __shared__ float part[128];
  int d = threadIdx.x & 63, h = threadIdx.x >> 6;
  float s = 0.f;
  for (int m = 0; m < MM; ++m){
    if (h == 0) s += bd[m*DECF + d];
    const float* t = T + (size_t)m*H1*DECF + d;
    for (int k = h*(H1/2); k < (h+1)*(H1/2); ++k){
      float a = g1[m*H1+k]*rsqrtf(v1[m*H1+k]+EPSBN);
      float c = (b1[m*H1+k]-m1[m*H1+k])*a + be1[m*H1+k];
      s += c*t[(size_t)k*DECF];
    }
    const float* wd = Wd + (size_t)m*LAT*DECF + d;
    for (int l = h*(LAT/2); l < (h+1)*(LAT/2); ++l){
      float a = g2[m*LAT+l]*rsqrtf(v2[m*LAT+l]+EPSBN);
      float c = (b2[m*LAT+l]-m2[m*LAT+l])*a + be2[m*LAT+l];
      s += c*wd[(size_t)l*DECF];
    }
  }
  part[threadIdx.x] = s;
  __syncthreads();
  if (h == 0) cbar[d] = 0.5f*(part[d] + part[64+d]);
}

__global__ __launch_bounds__(1024) void scan1(const int* __restrict__ deg, int* __restrict__ rp,
                      int* __restrict__ bsum, int n){
  __shared__ int sm[1024];
  int i = blockIdx.x*1024 + threadIdx.x;
  int v = (i < n) ? deg[i] : 0;
  sm[threadIdx.x] = v; __syncthreads();
  for (int off=1; off<1024; off<<=1){
    int t = (threadIdx.x >= off) ? sm[threadIdx.x-off] : 0;
    __syncthreads();
    sm[threadIdx.x] += t;
    __syncthreads();
  }
  if (i < n) rp[i] = sm[threadIdx.x] - v;
  if (threadIdx.x == 1023) bsum[blockIdx.x] = sm[1023];
}

__global__ void scan3n(int* __restrict__ rp, const int* __restrict__ bsum,
                       const int* __restrict__ dout, const int* __restrict__ din,
                       float* __restrict__ csrc, float* __restrict__ cdst){
  int i = blockIdx.x*blockDim.x + threadIdx.x;
  if (i >= NN) return;
  int b = i >> 10;
  int base = 0;
  for (int j = 0; j < b; ++j) base += bsum[j];
  rp[i] += base;
  if (i == NN-1) rp[NN] = EE;
  int a = dout[i]; if (a < 1) a = 1;
  int dd = din[i]; if (dd < 1) dd = 1;
  csrc[i] = rsqrtf((float)a);
  cdst[i] = rsqrtf((float)dd);
}

__global__ void scatk(const int* __restrict__ src,const int* __restrict__ dst,
                      const int* __restrict__ rp,int* __restrict__ cur,int* __restrict__ ss){
  int e = blockIdx.x*blockDim.x + threadIdx.x;
  if (e >= EE) return;
  int d = dst[e];
  int p = rp[d] + atomicAdd(&cur[d], 1);
  ss[p] = src[e];
}

// ---- fused GEMM (768 ticket blocks) + degree histogram (256 trailing blocks) ----
// nf_raw[n][d] = bf16( 0.5*sum_m x_m[n,:]@Weff_m[:,d] + cbar[d] )   (csrc applied in fgd1)
__global__ __launch_bounds__(256,4) void gemm_deg(
    const float* __restrict__ x, const short8v* __restrict__ WB,
    const float* __restrict__ cbar,
    unsigned short* __restrict__ nfb, int* __restrict__ ticket,
    const int* __restrict__ src, const int* __restrict__ dst,
    int* __restrict__ dout, int* __restrict__ din)
{
  if (blockIdx.x >= GEMM_BLKS){
    int t0 = (blockIdx.x - GEMM_BLKS)*256 + threadIdx.x;
    for (int e = t0; e < EE; e += 256*DEG_BLKS){
      atomicAdd(&dout[src[e]], 1);
      atomicAdd(&din[dst[e]], 1);
    }
    return;
  }
  const int lane = threadIdx.x & 63;
  const int r = lane & 15;
  const int kg = (lane >> 4) << 3;             // k-slot base: 0,8,16,24
  const int rg = (lane >> 4) << 2;             // D row group: 0,4,8,12
  const float cb0 = cbar[r], cb1 = cbar[16+r], cb2 = cbar[32+r], cb3 = cbar[48+r];

  while (true){
    int t = 0;
    if (lane == 0) t = atomicAdd(ticket, 1);
    t = __shfl(t, 0, 64);
    if (t >= NTILES) break;
    const int n0 = t*16;
    const float* xrow = x + (size_t)(n0 + r) * DIN;

    f32x4 acc0 = {0.f,0.f,0.f,0.f}, acc1 = acc0, acc2 = acc0, acc3 = acc0;
    f32x4 A0c, A1c; short8v B0c, B1c, B2c, B3c;
    {
      const float* p = xrow + kg;
      A0c = *(const f32x4*)p; A1c = *(const f32x4*)(p+4);
      const short8v* bp = WB + lane;
      B0c = bp[0]; B1c = bp[64]; B2c = bp[128]; B3c = bp[192];
    }
    for (int s = 0; s < KSTEPS-1; ++s){
      f32x4 A0n, A1n; short8v B0n, B1n, B2n, B3n;
      {
        int kr = (s+1)*32 + kg;
        const float* p = (kr < DIN) ? (xrow + kr)
                                    : (xrow + (size_t)(NN-1)*DIN + kr); // modality 1
        A0n = *(const f32x4*)p; A1n = *(const f32x4*)(p+4);
        const short8v* bp = WB + (size_t)(s+1)*256 + lane;
        B0n = bp[0]; B1n = bp[64]; B2n = bp[128]; B3n = bp[192];
      }
      union { short8v v; unsigned int u[4]; } AF;
      AF.u[0]=pkbf(A0c[0],A0c[1]); AF.u[1]=pkbf(A0c[2],A0c[3]);
      AF.u[2]=pkbf(A1c[0],A1c[1]); AF.u[3]=pkbf(A1c[2],A1c[3]);
      acc0 = __builtin_amdgcn_mfma_f32_16x16x32_bf16(AF.v, B0c, acc0, 0,0,0);
      acc1 = __builtin_amdgcn_mfma_f32_16x16x32_bf16(AF.v, B1c, acc1, 0,0,0);
      acc2 = __builtin_amdgcn_mfma_f32_16x16x32_bf16(AF.v, B2c, acc2, 0,0,0);
      acc3 = __builtin_amdgcn_mfma_f32_16x16x32_bf16(AF.v, B3c, acc3, 0,0,0);
      A0c=A0n; A1c=A1n; B0c=B0n; B1c=B1n; B2c=B2n; B3c=B3n;
    }
    {
      union { short8v v; unsigned int u[4]; } AF;
      AF.u[0]=pkbf(A0c[0],A0c[1]); AF.u[1]=pkbf(A0c[2],A0c[3]);
      AF.u[2]=pkbf(A1c[0],A1c[1]); AF.u[3]=pkbf(A1c[2],A1c[3]);
      acc0 = __builtin_amdgcn_mfma_f32_16x16x32_bf16(AF.v, B0c, acc0, 0,0,0);
      acc1 = __builtin_amdgcn_mfma_f32_16x16x32_bf16(AF.v, B1c, acc1, 0,0,0);
      acc2 = __builtin_amdgcn_mfma_f32_16x16x32_bf16(AF.v, B2c, acc2, 0,0,0);
      acc3 = __builtin_amdgcn_mfma_f32_16x16x32_bf16(AF.v, B3c, acc3, 0,0,0);
    }
    #pragma unroll
    for (int rr = 0; rr < 4; ++rr){
      int rowD = n0 + rg + rr;
      unsigned short* o = nfb + (size_t)rowD*64 + r;
      o[0]  = pk1(acc0[rr] + cb0);
      o[16] = pk1(acc1[rr] + cb1);
      o[32] = pk1(acc2[rr] + cb2);
      o[48] = pk1(acc3[rr] + cb3);
    }
  }
}

// 16B-per-lane gather accumulate: 8 lanes cover one 128B row
#define ACC_CS8(sv, idx) { float c_ = csrc[idx]; \
  u32x4 w_ = *(const u32x4*)(nfb + (size_t)(idx)*64 + cc); \
  sv[0] += c_*bfe0(w_.x); sv[1] += c_*bfe1(w_.x); \
  sv[2] += c_*bfe0(w_.y); sv[3] += c_*bfe1(w_.y); \
  sv[4] += c_*bfe0(w_.z); sv[5] += c_*bfe1(w_.z); \
  sv[6] += c_*bfe0(w_.w); sv[7] += c_*bfe1(w_.w); }

#define ACC_NC8(sv, idx) { \
  u32x4 w_ = *(const u32x4*)(hpb + (size_t)(idx)*64 + cc); \
  sv[0] += bfe0(w_.x); sv[1] += bfe1(w_.x); \
  sv[2] += bfe0(w_.y); sv[3] += bfe1(w_.y); \
  sv[4] += bfe0(w_.z); sv[5] += bfe1(w_.z); \
  sv[6] += bfe0(w_.w); sv[7] += bfe1(w_.w); }

// ---- fused gather(csrc-scaled, bf16) + dense1 -> hp (bf16) ----
__global__ __launch_bounds__(512,4) void fgd1(const unsigned short* __restrict__ nfb,
                      const int* __restrict__ rp,const int* __restrict__ ss,
                      const float* __restrict__ Wg1,const float* __restrict__ bg1,
                      const float* __restrict__ csrc,const float* __restrict__ cdst,
                      unsigned short* __restrict__ hpb){
  __shared__ float W[64*64];
  for (int i = threadIdx.x; i < 64*64; i += 512) W[i] = Wg1[i];
  __syncthreads();
  int wave = threadIdx.x >> 6, lane = threadIdx.x & 63;
  int q = lane >> 3, cc = (lane & 7)*8;        // 8 ushorts (16B) per lane, 8 q-groups
  const int NW = 512*8;                        // 4096 waves
  for (int n = blockIdx.x*8 + wave; n < NN; n += NW){
    int beg = rp[n], end = rp[n+1];
    f32x8 s8 = {0.f,0.f,0.f,0.f,0.f,0.f,0.f,0.f};
    int e = beg + q;
    for (; e + 24 < end; e += 32){             // 4 rows in flight per lane (8 per q-set)
      int i0 = ss[e], i1 = ss[e+8], i2 = ss[e+16], i3 = ss[e+24];
      ACC_CS8(s8,i0); ACC_CS8(s8,i1); ACC_CS8(s8,i2); ACC_CS8(s8,i3);
    }
    for (; e < end; e += 8){ int i0 = ss[e]; ACC_CS8(s8,i0); }
    // reduce across the 8 q-groups
    #pragma unroll
    for (int j = 0; j < 8; ++j) s8[j] += __shfl_xor(s8[j], 8);
    #pragma unroll
    for (int j = 0; j < 8; ++j) s8[j] += __shfl_xor(s8[j], 16);
    #pragma unroll
    for (int j = 0; j < 8; ++j) s8[j] += __shfl_xor(s8[j], 32);
    float acc = 0.f;
    #pragma unroll
    for (int l8 = 0; l8 < 8; ++l8){
      #pragma unroll
      for (int j = 0; j < 8; ++j)
        acc += __shfl(s8[j], l8, 64) * W[(8*l8+j)*64 + lane];
    }
    float h = fmaxf(cdst[n]*acc + bg1[lane], 0.f) * csrc[n];
    hpb[(size_t)n*64 + lane] = pk1(h);
  }
}

// ---- fused gather(bf16, pre-scaled hp) + dense2 -> score (fp32) ----
__global__ __launch_bounds__(512,4) void fgd2(const unsigned short* __restrict__ hpb,
                      const int* __restrict__ rp,const int* __restrict__ ss,
                      const float* __restrict__ Wg2,const float* __restrict__ bg2,
                      const float* __restrict__ cdst,float* __restrict__ score){
  __shared__ float W[64*16];
  for (int i = threadIdx.x; i < 64*16; i += 512) W[i] = Wg2[i];
  __syncthreads();
  int wave = threadIdx.x >> 6, lane = threadIdx.x & 63;
  int q = lane >> 3, cc = (lane & 7)*8;
  const int NW = 512*8;
  for (int n = blockIdx.x*8 + wave; n < NN; n += NW){
    int beg = rp[n], end = rp[n+1];
    f32x8 s8 = {0.f,0.f,0.f,0.f,0.f,0.f,0.f,0.f};
    int e = beg + q;
    for (; e + 24 < end; e += 32){
      int i0 = ss[e], i1 = ss[e+8], i2 = ss[e+16], i3 = ss[e+24];
      ACC_NC8(s8,i0); ACC_NC8(s8,i1); ACC_NC8(s8,i2); ACC_NC8(s8,i3);
    }
    for (; e < end; e += 8){ int i0 = ss[e]; ACC_NC8(s8,i0); }
    #pragma unroll
    for (int j = 0; j < 8; ++j) s8[j] += __shfl_xor(s8[j], 8);
    #pragma unroll
    for (int j = 0; j < 8; ++j) s8[j] += __shfl_xor(s8[j], 16);
    #pragma unroll
    for (int j = 0; j < 8; ++j) s8[j] += __shfl_xor(s8[j], 32);
    int c = lane & 15;
    float acc = 0.f;
    #pragma unroll
    for (int l8 = 0; l8 < 8; ++l8){
      #pragma unroll
      for (int j = 0; j < 8; ++j)
        acc += __shfl(s8[j], l8, 64) * W[(8*l8+j)*16 + c];
    }
    if (lane < 16) score[(size_t)n*16 + lane] = cdst[n]*acc + bg2[lane];
  }
}

extern "C" void kernel_launch(void* const* d_in, const int* in_sizes, int n_in,
                              void* d_out, int out_size, void* d_ws, size_t ws_size,
                              hipStream_t stream){
  const float* x   = (const float*)d_in[0];
  const int* src   = (const int*)d_in[1];
  const int* dst   = (const int*)d_in[2];
  const float* W1  = (const float*)d_in[3];
  const float* b1  = (const float*)d_in[4];
  const float* g1  = (const float*)d_in[5];
  const float* be1 = (const float*)d_in[6];
  const float* m1  = (const float*)d_in[7];
  const float* v1  = (const float*)d_in[8];
  const float* W2  = (const float*)d_in[9];
  const float* b2  = (const float*)d_in[10];
  const float* g2  = (const float*)d_in[11];
  const float* be2 = (const float*)d_in[12];
  const float* m2  = (const float*)d_in[13];
  const float* v2  = (const float*)d_in[14];
  const float* Wd  = (const float*)d_in[15];
  const float* bd  = (const float*)d_in[16];
  const float* Wg1 = (const float*)d_in[17];
  const float* bg1 = (const float*)d_in[18];
  const float* Wg2 = (const float*)d_in[19];
  const float* bg2 = (const float*)d_in[20];
  float* score = (float*)d_out;

  char* w = (char*)d_ws;
  size_t off = 0;
  auto alc = [&](size_t b){ size_t c = off; off += (b + 255) & ~(size_t)255; return c; };
  // zero-init region: dout, din, cur, ticket (single memset)
  size_t o_dout = alc((size_t)NN*4), o_din = alc((size_t)NN*4), o_cur = alc((size_t)NN*4);
  size_t o_tick = alc(256);
  size_t zspan = off;
  size_t o_rp  = alc((size_t)(NN+1)*4), o_bsum = alc(256*4);
  size_t o_csrc = alc((size_t)NN*4), o_cdst = alc((size_t)NN*4);
  size_t o_T = alc((size_t)MM*H1*DECF*4), o_cbar = alc(DECF*4);
  size_t o_WB = alc((size_t)MM*DIN*DECF*2);
  size_t o_ss = alc((size_t)EE*4);
  size_t o_nf = alc((size_t)NN*64*2);   // bf16
  size_t o_hp = alc((size_t)NN*64*2);   // bf16

  int* dout = (int*)(w+o_dout); int* din = (int*)(w+o_din); int* cur = (int*)(w+o_cur);
  int* tick = (int*)(w+o_tick);
  int* rp = (int*)(w+o_rp); int* bsum = (int*)(w+o_bsum);
  float* csrc = (float*)(w+o_csrc); float* cdst = (float*)(w+o_cdst);
  float* T = (float*)(w+o_T); float* cbar = (float*)(w+o_cbar);
  int* ss = (int*)(w+o_ss);
  unsigned short* nfb = (unsigned short*)(w+o_nf);
  unsigned short* hpb = (unsigned short*)(w+o_hp);

  hipMemsetAsync(w, 0, zspan, stream);

  prepA<<<(MM*H1*DECF)/256,256,0,stream>>>(W2,Wd,g2,v2,T);
  prepB<<<(MM*DIN*DECF)/256,256,0,stream>>>(W1,g1,v1,T,(unsigned short*)(w+o_WB));
  prepC<<<1,128,0,stream>>>(b1,g1,be1,m1,v1,b2,g2,be2,m2,v2,T,Wd,bd,cbar);

  gemm_deg<<<GEMM_BLKS+DEG_BLKS,256,0,stream>>>(x,(const short8v*)(w+o_WB),cbar,
                                                nfb,tick,src,dst,dout,din);

  int nb = (NN+1023)/1024;
  scan1<<<nb,1024,0,stream>>>(din,rp,bsum,NN);
  scan3n<<<(NN+255)/256,256,0,stream>>>(rp,bsum,dout,din,csrc,cdst);
  scatk<<<(EE+255)/256,256,0,stream>>>(src,dst,rp,cur,ss);

  fgd1<<<512,512,0,stream>>>(nfb,rp,ss,Wg1,bg1,csrc,cdst,hpb);
  fgd2<<<512,512,0,stream>>>(hpb,rp,ss,Wg2,bg2,cdst,score);
}

// Round 7
// 702.481 us; speedup vs baseline: 1.3495x; 1.0177x over previous
//
#include <hip/hip_runtime.h>

#define NN 50000
#define EE 1600000
#define MM 2
#define DIN 2000
#define H1 500
#define LAT 128
#define DECF 64
#define KTOT (MM*DIN)        // 4000
#define KSTEPS (KTOT/32)     // 125
#define NTILES (NN/16)       // 3125 exact
#define GEMM_BLKS 768
#define DEG_BLKS 256
#define EPSBN 1e-5f

typedef float f32x4 __attribute__((ext_vector_type(4)));
typedef short short8v __attribute__((ext_vector_type(8)));
typedef unsigned int u32x2 __attribute__((ext_vector_type(2)));

__device__ __forceinline__ unsigned int pkbf(float a, float b){
  unsigned int ua = __float_as_uint(a), ub = __float_as_uint(b);
  ua = (ua + 0x7FFFu + ((ua>>16)&1u)) >> 16;
  ub = (ub + 0x7FFFu + ((ub>>16)&1u)) & 0xFFFF0000u;
  return ua | ub;
}
__device__ __forceinline__ unsigned short pk1(float a){
  unsigned int u = __float_as_uint(a);
  return (unsigned short)((u + 0x7FFFu + ((u>>16)&1u)) >> 16);
}
__device__ __forceinline__ float bfe0(unsigned int w){ return __uint_as_float(w<<16); }
__device__ __forceinline__ float bfe1(unsigned int w){ return __uint_as_float(w & 0xFFFF0000u); }

// ---- prepA: T[m][k][d] = sum_l W2[m][k][l]*a2[m][l]*Wd[m][l][d], a2 inline ----
__global__ __launch_bounds__(256) void prepA(const float* __restrict__ W2,const float* __restrict__ Wd,
                      const float* __restrict__ g2,const float* __restrict__ v2,
                      float* __restrict__ T){
  __shared__ float a2[LAT];
  int m = (blockIdx.x*4) / H1;
  if (threadIdx.x < LAT)
    a2[threadIdx.x] = g2[m*LAT+threadIdx.x]*rsqrtf(v2[m*LAT+threadIdx.x]+EPSBN);
  __syncthreads();
  int g = blockIdx.x*256 + threadIdx.x;     // grid exact: 64000/256 = 250
  int d = g & 63; int mk = g >> 6; int k = mk % H1;
  const float* w2 = W2 + (size_t)(m*H1 + k)*LAT;
  const float* wd = Wd + (size_t)m*LAT*DECF + d;
  float acc = 0.f;
  for (int l = 0; l < LAT; ++l) acc += w2[l]*a2[l]*wd[(size_t)l*DECF];
  T[g] = acc;
}

// ---- prepB: Weff (bf16, B-fragment order), a1 inline ----
__global__ __launch_bounds__(256) void prepB(const float* __restrict__ W1,const float* __restrict__ g1,
                      const float* __restrict__ v1,const float* __restrict__ T,
                      unsigned short* __restrict__ WB){
  __shared__ float a1[H1];
  int m = (blockIdx.x*4) / DIN;
  for (int k = threadIdx.x; k < H1; k += 256)
    a1[k] = g1[m*H1+k]*rsqrtf(v1[m*H1+k]+EPSBN);
  __syncthreads();
  int g = blockIdx.x*256 + threadIdx.x;     // grid exact: 256000/256 = 1000
  int d = g & 63; int mi = g >> 6; int i = mi % DIN;
  const float* w1 = W1 + (size_t)(m*DIN + i)*H1;
  const float* t  = T + (size_t)m*H1*DECF + d;
  float acc = 0.f;
  for (int k = 0; k < H1; ++k) acc += w1[k]*a1[k]*t[(size_t)k*DECF];
  acc *= 0.5f;
  unsigned int u = __float_as_uint(acc);
  unsigned short bf = (unsigned short)((u + 0x7FFFu + ((u>>16)&1u)) >> 16);
  int kc = m*DIN + i;
  int s = kc >> 5, kl = kc & 31;
  int laneB = ((kl>>3)<<4) | (d & 15);
  int t4 = d >> 4;
  WB[((size_t)((s*4 + t4)*64 + laneB))*8 + (kl & 7)] = bf;
}

// ---- prepC: cbar[d] = 0.5 * sum_m ( c1@T + c2@Wd + bd ) ----
__global__ void prepC(const float* __restrict__ b1,const float* __restrict__ g1,const float* __restrict__ be1,
                      const float* __restrict__ m1,const float* __restrict__ v1,
                      const float* __restrict__ b2,const float* __restrict__ g2,const float* __restrict__ be2,
                      const float* __restrict__ m2,const float* __restrict__ v2,
                      const float* __restrict__ T,const float* __restrict__ Wd,
                      const float* __restrict__ bd, float* __restrict__ cbar){
  __shared__ float part[128];
  int d = threadIdx.x & 63, h = threadIdx.x >> 6;
  float s = 0.f;
  for (int m = 0; m < MM; ++m){
    if (h == 0) s += bd[m*DECF + d];
    const float* t = T + (size_t)m*H1*DECF + d;
    for (int k = h*(H1/2); k < (h+1)*(H1/2); ++k){
      float a = g1[m*H1+k]*rsqrtf(v1[m*H1+k]+EPSBN);
      float c = (b1[m*H1+k]-m1[m*H1+k])*a + be1[m*H1+k];
      s += c*t[(size_t)k*DECF];
    }
    const float* wd = Wd + (size_t)m*LAT*DECF + d;
    for (int l = h*(LAT/2); l < (h+1)*(LAT/2); ++l){
      float a = g2[m*LAT+l]*rsqrtf(v2[m*LAT+l]+EPSBN);
      float c = (b2[m*LAT+l]-m2[m*LAT+l])*a + be2[m*LAT+l];
      s += c*wd[(size_t)l*DECF];
    }
  }
  part[threadIdx.x] = s;
  __syncthreads();
  if (h == 0) cbar[d] = 0.5f*(part[d] + part[64+d]);
}

__global__ __launch_bounds__(1024) void scan1(const int* __restrict__ deg, int* __restrict__ rp,
                      int* __restrict__ bsum, int n){
  __shared__ int sm[1024];
  int i = blockIdx.x*1024 + threadIdx.x;
  int v = (i < n) ? deg[i] : 0;
  sm[threadIdx.x] = v; __syncthreads();
  for (int off=1; off<1024; off<<=1){
    int t = (threadIdx.x >= off) ? sm[threadIdx.x-off] : 0;
    __syncthreads();
    sm[threadIdx.x] += t;
    __syncthreads();
  }
  if (i < n) rp[i] = sm[threadIdx.x] - v;
  if (threadIdx.x == 1023) bsum[blockIdx.x] = sm[1023];
}

__global__ void scan3n(int* __restrict__ rp, const int* __restrict__ bsum,
                       const int* __restrict__ dout, const int* __restrict__ din,
                       float* __restrict__ csrc, float* __restrict__ cdst){
  int i = blockIdx.x*blockDim.x + threadIdx.x;
  if (i >= NN) return;
  int b = i >> 10;
  int base = 0;
  for (int j = 0; j < b; ++j) base += bsum[j];
  rp[i] += base;
  if (i == NN-1) rp[NN] = EE;
  int a = dout[i]; if (a < 1) a = 1;
  int dd = din[i]; if (dd < 1) dd = 1;
  csrc[i] = rsqrtf((float)a);
  cdst[i] = rsqrtf((float)dd);
}

__global__ void scatk(const int* __restrict__ src,const int* __restrict__ dst,
                      const int* __restrict__ rp,int* __restrict__ cur,int* __restrict__ ss){
  int e = blockIdx.x*blockDim.x + threadIdx.x;
  if (e >= EE) return;
  int d = dst[e];
  int p = rp[d] + atomicAdd(&cur[d], 1);
  ss[p] = src[e];
}

// ---- fused GEMM (768 ticket blocks) + degree histogram (256 trailing blocks) ----
// nf_raw[n][d] = bf16( 0.5*sum_m x_m[n,:]@Weff_m[:,d] + cbar[d] )   (csrc applied in fgd1)
__global__ __launch_bounds__(256,4) void gemm_deg(
    const float* __restrict__ x, const short8v* __restrict__ WB,
    const float* __restrict__ cbar,
    unsigned short* __restrict__ nfb, int* __restrict__ ticket,
    const int* __restrict__ src, const int* __restrict__ dst,
    int* __restrict__ dout, int* __restrict__ din)
{
  if (blockIdx.x >= GEMM_BLKS){
    int t0 = (blockIdx.x - GEMM_BLKS)*256 + threadIdx.x;
    for (int e = t0; e < EE; e += 256*DEG_BLKS){
      atomicAdd(&dout[src[e]], 1);
      atomicAdd(&din[dst[e]], 1);
    }
    return;
  }
  const int lane = threadIdx.x & 63;
  const int r = lane & 15;
  const int kg = (lane >> 4) << 3;             // k-slot base: 0,8,16,24
  const int rg = (lane >> 4) << 2;             // D row group: 0,4,8,12
  const float cb0 = cbar[r], cb1 = cbar[16+r], cb2 = cbar[32+r], cb3 = cbar[48+r];

  while (true){
    int t = 0;
    if (lane == 0) t = atomicAdd(ticket, 1);
    t = __shfl(t, 0, 64);
    if (t >= NTILES) break;
    const int n0 = t*16;
    const float* xrow = x + (size_t)(n0 + r) * DIN;

    f32x4 acc0 = {0.f,0.f,0.f,0.f}, acc1 = acc0, acc2 = acc0, acc3 = acc0;
    f32x4 A0c, A1c; short8v B0c, B1c, B2c, B3c;
    {
      const float* p = xrow + kg;
      A0c = *(const f32x4*)p; A1c = *(const f32x4*)(p+4);
      const short8v* bp = WB + lane;
      B0c = bp[0]; B1c = bp[64]; B2c = bp[128]; B3c = bp[192];
    }
    for (int s = 0; s < KSTEPS-1; ++s){
      f32x4 A0n, A1n; short8v B0n, B1n, B2n, B3n;
      {
        int kr = (s+1)*32 + kg;
        const float* p = (kr < DIN) ? (xrow + kr)
                                    : (xrow + (size_t)(NN-1)*DIN + kr); // modality 1
        A0n = *(const f32x4*)p; A1n = *(const f32x4*)(p+4);
        const short8v* bp = WB + (size_t)(s+1)*256 + lane;
        B0n = bp[0]; B1n = bp[64]; B2n = bp[128]; B3n = bp[192];
      }
      union { short8v v; unsigned int u[4]; } AF;
      AF.u[0]=pkbf(A0c[0],A0c[1]); AF.u[1]=pkbf(A0c[2],A0c[3]);
      AF.u[2]=pkbf(A1c[0],A1c[1]); AF.u[3]=pkbf(A1c[2],A1c[3]);
      acc0 = __builtin_amdgcn_mfma_f32_16x16x32_bf16(AF.v, B0c, acc0, 0,0,0);
      acc1 = __builtin_amdgcn_mfma_f32_16x16x32_bf16(AF.v, B1c, acc1, 0,0,0);
      acc2 = __builtin_amdgcn_mfma_f32_16x16x32_bf16(AF.v, B2c, acc2, 0,0,0);
      acc3 = __builtin_amdgcn_mfma_f32_16x16x32_bf16(AF.v, B3c, acc3, 0,0,0);
      A0c=A0n; A1c=A1n; B0c=B0n; B1c=B1n; B2c=B2n; B3c=B3n;
    }
    {
      union { short8v v; unsigned int u[4]; } AF;
      AF.u[0]=pkbf(A0c[0],A0c[1]); AF.u[1]=pkbf(A0c[2],A0c[3]);
      AF.u[2]=pkbf(A1c[0],A1c[1]); AF.u[3]=pkbf(A1c[2],A1c[3]);
      acc0 = __builtin_amdgcn_mfma_f32_16x16x32_bf16(AF.v, B0c, acc0, 0,0,0);
      acc1 = __builtin_amdgcn_mfma_f32_16x16x32_bf16(AF.v, B1c, acc1, 0,0,0);
      acc2 = __builtin_amdgcn_mfma_f32_16x16x32_bf16(AF.v, B2c, acc2, 0,0,0);
      acc3 = __builtin_amdgcn_mfma_f32_16x16x32_bf16(AF.v, B3c, acc3, 0,0,0);
    }
    #pragma unroll
    for (int rr = 0; rr < 4; ++rr){
      int rowD = n0 + rg + rr;
      unsigned short* o = nfb + (size_t)rowD*64 + r;
      o[0]  = pk1(acc0[rr] + cb0);
      o[16] = pk1(acc1[rr] + cb1);
      o[32] = pk1(acc2[rr] + cb2);
      o[48] = pk1(acc3[rr] + cb3);
    }
  }
}

// ---- fused gather(csrc-scaled, bf16) + dense1 -> hp (bf16) ----
// hp[n][j] = bf16( relu(cdst[n]*(sum_e csrc[src_e]*nf[src_e])@Wg1[j] + bg1[j]) * csrc[n] )
__global__ __launch_bounds__(512,4) void fgd1(const unsigned short* __restrict__ nfb,
                      const int* __restrict__ rp,const int* __restrict__ ss,
                      const float* __restrict__ Wg1,const float* __restrict__ bg1,
                      const float* __restrict__ csrc,const float* __restrict__ cdst,
                      unsigned short* __restrict__ hpb){
  __shared__ float W[64*64];
  for (int i = threadIdx.x; i < 64*64; i += 512) W[i] = Wg1[i];
  __syncthreads();
  int wave = threadIdx.x >> 6, lane = threadIdx.x & 63;
  int q = lane >> 4, cc = (lane & 15)*4;       // 4 ushorts (8B) per lane
  const int NW = 512*8;                        // total waves
  for (int n = blockIdx.x*8 + wave; n < NN; n += NW){
    int beg = rp[n], end = rp[n+1];
    f32x4 s4 = {0.f,0.f,0.f,0.f};
    int e = beg + q;
    for (; e + 12 < end; e += 16){
      int i0 = ss[e], i1 = ss[e+4], i2 = ss[e+8], i3 = ss[e+12];
      float c0 = csrc[i0], c1 = csrc[i1], c2 = csrc[i2], c3 = csrc[i3];
      u32x2 w0 = *(const u32x2*)(nfb + (size_t)i0*64 + cc);
      u32x2 w1 = *(const u32x2*)(nfb + (size_t)i1*64 + cc);
      u32x2 w2 = *(const u32x2*)(nfb + (size_t)i2*64 + cc);
      u32x2 w3 = *(const u32x2*)(nfb + (size_t)i3*64 + cc);
      s4.x += c0*bfe0(w0.x) + c1*bfe0(w1.x) + c2*bfe0(w2.x) + c3*bfe0(w3.x);
      s4.y += c0*bfe1(w0.x) + c1*bfe1(w1.x) + c2*bfe1(w2.x) + c3*bfe1(w3.x);
      s4.z += c0*bfe0(w0.y) + c1*bfe0(w1.y) + c2*bfe0(w2.y) + c3*bfe0(w3.y);
      s4.w += c0*bfe1(w0.y) + c1*bfe1(w1.y) + c2*bfe1(w2.y) + c3*bfe1(w3.y);
    }
    for (; e < end; e += 4){
      int i0 = ss[e]; float c0 = csrc[i0];
      u32x2 w0 = *(const u32x2*)(nfb + (size_t)i0*64 + cc);
      s4.x += c0*bfe0(w0.x); s4.y += c0*bfe1(w0.x);
      s4.z += c0*bfe0(w0.y); s4.w += c0*bfe1(w0.y);
    }
    s4.x += __shfl_xor(s4.x,16); s4.y += __shfl_xor(s4.y,16);
    s4.z += __shfl_xor(s4.z,16); s4.w += __shfl_xor(s4.w,16);
    s4.x += __shfl_xor(s4.x,32); s4.y += __shfl_xor(s4.y,32);
    s4.z += __shfl_xor(s4.z,32); s4.w += __shfl_xor(s4.w,32);
    float acc = 0.f;
    #pragma unroll
    for (int l16 = 0; l16 < 16; ++l16){
      acc += __shfl(s4.x,l16) * W[(4*l16+0)*64 + lane];
      acc += __shfl(s4.y,l16) * W[(4*l16+1)*64 + lane];
      acc += __shfl(s4.z,l16) * W[(4*l16+2)*64 + lane];
      acc += __shfl(s4.w,l16) * W[(4*l16+3)*64 + lane];
    }
    float h = fmaxf(cdst[n]*acc + bg1[lane], 0.f) * csrc[n];
    hpb[(size_t)n*64 + lane] = pk1(h);
  }
}

// ---- fused gather(bf16, pre-scaled hp) + dense2 -> score (fp32) ----
__global__ __launch_bounds__(512,4) void fgd2(const unsigned short* __restrict__ hpb,
                      const int* __restrict__ rp,const int* __restrict__ ss,
                      const float* __restrict__ Wg2,const float* __restrict__ bg2,
                      const float* __restrict__ cdst,float* __restrict__ score){
  __shared__ float W[64*16];
  for (int i = threadIdx.x; i < 64*16; i += 512) W[i] = Wg2[i];
  __syncthreads();
  int wave = threadIdx.x >> 6, lane = threadIdx.x & 63;
  int q = lane >> 4, cc = (lane & 15)*4;
  const int NW = 512*8;
  for (int n = blockIdx.x*8 + wave; n < NN; n += NW){
    int beg = rp[n], end = rp[n+1];
    f32x4 s4 = {0.f,0.f,0.f,0.f};
    int e = beg + q;
    for (; e + 12 < end; e += 16){
      int i0 = ss[e], i1 = ss[e+4], i2 = ss[e+8], i3 = ss[e+12];
      u32x2 w0 = *(const u32x2*)(hpb + (size_t)i0*64 + cc);
      u32x2 w1 = *(const u32x2*)(hpb + (size_t)i1*64 + cc);
      u32x2 w2 = *(const u32x2*)(hpb + (size_t)i2*64 + cc);
      u32x2 w3 = *(const u32x2*)(hpb + (size_t)i3*64 + cc);
      s4.x += bfe0(w0.x) + bfe0(w1.x) + bfe0(w2.x) + bfe0(w3.x);
      s4.y += bfe1(w0.x) + bfe1(w1.x) + bfe1(w2.x) + bfe1(w3.x);
      s4.z += bfe0(w0.y) + bfe0(w1.y) + bfe0(w2.y) + bfe0(w3.y);
      s4.w += bfe1(w0.y) + bfe1(w1.y) + bfe1(w2.y) + bfe1(w3.y);
    }
    for (; e < end; e += 4){
      u32x2 w0 = *(const u32x2*)(hpb + (size_t)ss[e]*64 + cc);
      s4.x += bfe0(w0.x); s4.y += bfe1(w0.x);
      s4.z += bfe0(w0.y); s4.w += bfe1(w0.y);
    }
    s4.x += __shfl_xor(s4.x,16); s4.y += __shfl_xor(s4.y,16);
    s4.z += __shfl_xor(s4.z,16); s4.w += __shfl_xor(s4.w,16);
    s4.x += __shfl_xor(s4.x,32); s4.y += __shfl_xor(s4.y,32);
    s4.z += __shfl_xor(s4.z,32); s4.w += __shfl_xor(s4.w,32);
    int c = lane & 15;
    float acc = 0.f;
    #pragma unroll
    for (int l16 = 0; l16 < 16; ++l16){
      acc += __shfl(s4.x,l16) * W[(4*l16+0)*16 + c];
      acc += __shfl(s4.y,l16) * W[(4*l16+1)*16 + c];
      acc += __shfl(s4.z,l16) * W[(4*l16+2)*16 + c];
      acc += __shfl(s4.w,l16) * W[(4*l16+3)*16 + c];
    }
    if (lane < 16) score[(size_t)n*16 + lane] = cdst[n]*acc + bg2[lane];
  }
}

extern "C" void kernel_launch(void* const* d_in, const int* in_sizes, int n_in,
                              void* d_out, int out_size, void* d_ws, size_t ws_size,
                              hipStream_t stream){
  const float* x   = (const float*)d_in[0];
  const int* src   = (const int*)d_in[1];
  const int* dst   = (const int*)d_in[2];
  const float* W1  = (const float*)d_in[3];
  const float* b1  = (const float*)d_in[4];
  const float* g1  = (const float*)d_in[5];
  const float* be1 = (const float*)d_in[6];
  const float* m1  = (const float*)d_in[7];
  const float* v1  = (const float*)d_in[8];
  const float* W2  = (const float*)d_in[9];
  const float* b2  = (const float*)d_in[10];
  const float* g2  = (const float*)d_in[11];
  const float* be2 = (const float*)d_in[12];
  const float* m2  = (const float*)d_in[13];
  const float* v2  = (const float*)d_in[14];
  const float* Wd  = (const float*)d_in[15];
  const float* bd  = (const float*)d_in[16];
  const float* Wg1 = (const float*)d_in[17];
  const float* bg1 = (const float*)d_in[18];
  const float* Wg2 = (const float*)d_in[19];
  const float* bg2 = (const float*)d_in[20];
  float* score = (float*)d_out;

  char* w = (char*)d_ws;
  size_t off = 0;
  auto alc = [&](size_t b){ size_t c = off; off += (b + 255) & ~(size_t)255; return c; };
  // zero-init region: dout, din, cur, ticket (single memset)
  size_t o_dout = alc((size_t)NN*4), o_din = alc((size_t)NN*4), o_cur = alc((size_t)NN*4);
  size_t o_tick = alc(256);
  size_t zspan = off;
  size_t o_rp  = alc((size_t)(NN+1)*4), o_bsum = alc(256*4);
  size_t o_csrc = alc((size_t)NN*4), o_cdst = alc((size_t)NN*4);
  size_t o_T = alc((size_t)MM*H1*DECF*4), o_cbar = alc(DECF*4);
  size_t o_WB = alc((size_t)MM*DIN*DECF*2);
  size_t o_ss = alc((size_t)EE*4);
  size_t o_nf = alc((size_t)NN*64*2);   // bf16
  size_t o_hp = alc((size_t)NN*64*2);   // bf16

  int* dout = (int*)(w+o_dout); int* din = (int*)(w+o_din); int* cur = (int*)(w+o_cur);
  int* tick = (int*)(w+o_tick);
  int* rp = (int*)(w+o_rp); int* bsum = (int*)(w+o_bsum);
  float* csrc = (float*)(w+o_csrc); float* cdst = (float*)(w+o_cdst);
  float* T = (float*)(w+o_T); float* cbar = (float*)(w+o_cbar);
  int* ss = (int*)(w+o_ss);
  unsigned short* nfb = (unsigned short*)(w+o_nf);
  unsigned short* hpb = (unsigned short*)(w+o_hp);

  hipMemsetAsync(w, 0, zspan, stream);

  prepA<<<(MM*H1*DECF)/256,256,0,stream>>>(W2,Wd,g2,v2,T);
  prepB<<<(MM*DIN*DECF)/256,256,0,stream>>>(W1,g1,v1,T,(unsigned short*)(w+o_WB));
  prepC<<<1,128,0,stream>>>(b1,g1,be1,m1,v1,b2,g2,be2,m2,v2,T,Wd,bd,cbar);

  gemm_deg<<<GEMM_BLKS+DEG_BLKS,256,0,stream>>>(x,(const short8v*)(w+o_WB),cbar,
                                                nfb,tick,src,dst,dout,din);

  int nb = (NN+1023)/1024;
  scan1<<<nb,1024,0,stream>>>(din,rp,bsum,NN);
  scan3n<<<(NN+255)/256,256,0,stream>>>(rp,bsum,dout,din,csrc,cdst);
  scatk<<<(EE+255)/256,256,0,stream>>>(src,dst,rp,cur,ss);

  fgd1<<<512,512,0,stream>>>(nfb,rp,ss,Wg1,bg1,csrc,cdst,hpb);
  fgd2<<<512,512,0,stream>>>(hpb,rp,ss,Wg2,bg2,cdst,score);
}